// Round 8
// baseline (1121.267 us; speedup 1.0000x reference)
//
#include <hip/hip_runtime.h>
#include <math.h>

// EqualityConstraint: x_new = x - J^T G^{-1} F(x)
//   t = tanh(x); s = 1 - t^2; J = A diag(s)
//   F = A t + p; G = A diag(s^2) A^T  (SPD, M x M)
//   y = G^{-1} F;  x_new = x - s .* (A^T y)
//
// One 256-thread block per batch row; 16x16 thread grid, each thread an 8x8
// register tile of G -> L (blocked right-looking register Cholesky);
// compact triangular LDS L-tile buffer; distributed block triangular solves.
//
// VGPR BUDGET LAW (R1-R7, all measured): hipcc's effective cap on this
// toolchain is 256/N (granule 4) where N = __launch_bounds__ 2nd arg:
//   bound 2 -> 128 (natural alloc fits exactly, zero scratch)
//   bound 3 -> 84, bound 4 -> 64 -> acc[8][8] spills wholesale, GBs of
//   scratch traffic, kernel becomes scratch-BW-bound.
// OCCUPANCY LAW: 2nd arg pins waves/EU两-sided ({N,N}); R5's resources
// allowed 4 blocks but bound 2 held 22%. Therefore: OMIT the 2nd arg.
// With flat-work-group-size {256,256} only, alloc is natural (128) and
// residency is resource-derived: VGPR 128 -> 4 waves/SIMD; LDS 39936 B
// -> 4 blocks/CU -> 50% ceiling.
// BANK LAW (R5/R7): stage chunk-swizzle psi(i)=i+4*(i>>5), pitch 140
// -> 2-way (free). TSZ=68 tiles -> tile-base bank rotates -> 2-way.
// LDS: pool = max(stage 2240 + t 256 + s 256, L-tiles 136*68) = 9248
// floats (aliased; phase-disjoint) + side 704 floats = 39936 B total.

#define kN 256   // x dim
#define kM 128   // constraint dim
#define SP  140  // swizzled stage row pitch (floats); psi(127)=139 < 140
#define TSZ 68   // L-tile stride in floats (17 float4s)
#define RP  8    // reduction-slot pitch
#define TRI(I,K) ((((I) * ((I) + 1)) >> 1) + (K))   // lower-tri tile index, I>=K

__global__ __launch_bounds__(256)
void eqcon_kernel(const float* __restrict__ x,
                  const float* __restrict__ parms,
                  const float* __restrict__ A,
                  float* __restrict__ out)
{
    __shared__ float Fx_s[kM];
    __shared__ float z_s[kM];
    __shared__ float y_s[kM];
    __shared__ float invd_s[kM];
    __shared__ float Ld_s[64];
    __shared__ float red_s[16 * RP];
    // Phases 1-3: [0..2240) swizzled A-stage, [2240..2496) t, [2496..2752) s.
    // Phase 4+:  L tiles, tile (I,K) I>=K at TRI(I,K)*TSZ, col-major
    //            T[c*8+r] = L_tile[r][c]. Tile writes only reach the aliased
    //            region after stage/t/s are dead (post-phase-3 barrier).
    __shared__ float pool[136 * TSZ];   // 9248 floats = 36992 B

    const int tid = (int)threadIdx.x;
    const int b   = (int)blockIdx.x;
    const int ti  = tid & 15;   // row-tile index
    const int tk  = tid >> 4;   // col-tile index

    float* stage = pool;
    float* t_sh  = pool + 16 * SP;        // 2240
    float* s_sh  = pool + 16 * SP + kN;   // 2496

    // ---- Phase 1: t = tanh(x), s = sech^2(x) ----
    const float xv = x[b * kN + tid];
    const float tv = tanhf(xv);
    const float sv = 1.0f - tv * tv;
    t_sh[tid] = tv;
    s_sh[tid] = sv;
    __syncthreads();

    // ---- Phase 2: Fx = A t + parms (2 threads per row) ----
    {
        const int row  = tid >> 1;
        const int half = tid & 1;
        const float4* __restrict__ Ar =
            reinterpret_cast<const float4*>(A + row * kN + half * (kN / 2));
        const float4* Tr = reinterpret_cast<const float4*>(t_sh + half * (kN / 2));
        float sum = 0.0f;
#pragma unroll
        for (int q = 0; q < kN / 8; ++q) {
            const float4 a4 = Ar[q];
            const float4 t4 = Tr[q];
            sum += a4.x * t4.x + a4.y * t4.y + a4.z * t4.z + a4.w * t4.w;
        }
        sum += __shfl_xor(sum, 1);
        if (half == 0) Fx_s[row] = sum + parms[b * kM + row];
    }

    // ---- Phase 3: G = A diag(s^2) A^T, each thread an 8x8 register tile ----
    float acc[8][8];
#pragma unroll
    for (int r = 0; r < 8; ++r)
#pragma unroll
        for (int c = 0; c < 8; ++c) acc[r][c] = 0.0f;

    // swizzled read bases: chunk(i>>2) -> chunk + (chunk>>3), float4-aligned
    const int aoff = ti * 8 + ((ti >> 2) << 2);
    const int boff = tk * 8 + ((tk >> 2) << 2);

    for (int jt = 0; jt < kN; jt += 16) {
        __syncthreads();  // prev tile's compute done before overwriting stage
#pragma unroll
        for (int rep = 0; rep < 8; ++rep) {
            const int idx = rep * 256 + tid;
            const int i   = idx >> 4;
            const int jj  = idx & 15;
            stage[jj * SP + i + ((i >> 5) << 2)] = A[i * kN + (jt + jj)];
        }
        __syncthreads();
#pragma unroll
        for (int jj = 0; jj < 16; ++jj) {
            const float sj = s_sh[jt + jj];
            const float w  = sj * sj;
            const float* rowp = stage + jj * SP;
            const float4 a0 = *reinterpret_cast<const float4*>(rowp + aoff);
            const float4 a1 = *reinterpret_cast<const float4*>(rowp + aoff + 4);
            const float4 b0 = *reinterpret_cast<const float4*>(rowp + boff);
            const float4 b1 = *reinterpret_cast<const float4*>(rowp + boff + 4);
            const float av[8] = {a0.x, a0.y, a0.z, a0.w, a1.x, a1.y, a1.z, a1.w};
            const float bv[8] = {b0.x * w, b0.y * w, b0.z * w, b0.w * w,
                                 b1.x * w, b1.y * w, b1.z * w, b1.w * w};
#pragma unroll
            for (int r = 0; r < 8; ++r)
#pragma unroll
                for (int c = 0; c < 8; ++c) acc[r][c] += av[r] * bv[c];
        }
    }
    __syncthreads();  // stage/t/s dead; pool becomes the L-tile buffer

    float* Lt = pool;

    // ---- Phase 4: blocked register Cholesky; L tiles published to Lt ----
    for (int pb = 0; pb < 16; ++pb) {
        const int kb = pb * 8;
        if (ti == pb && tk == pb) {
            // 8x8 diagonal Cholesky in registers (lower triangle)
#pragma unroll
            for (int kk = 0; kk < 8; ++kk) {
                float d = fmaxf(acc[kk][kk], 1e-30f);
                const float rd  = sqrtf(d);
                const float inv = 1.0f / rd;
                invd_s[kb + kk] = inv;
                acc[kk][kk] = rd;
#pragma unroll
                for (int r = kk + 1; r < 8; ++r) acc[r][kk] *= inv;
#pragma unroll
                for (int r = kk + 1; r < 8; ++r)
#pragma unroll
                    for (int c = kk + 1; c <= r; ++c)
                        acc[r][c] -= acc[r][kk] * acc[c][kk];
            }
#pragma unroll
            for (int r = 0; r < 8; ++r)
#pragma unroll
                for (int c = 0; c < 8; ++c) Ld_s[r * 8 + c] = acc[r][c];
            float* T = Lt + TRI(pb, pb) * TSZ;
#pragma unroll
            for (int c = 0; c < 8; ++c) {
                const float4 lo = make_float4(acc[0][c], acc[1][c], acc[2][c], acc[3][c]);
                const float4 hi = make_float4(acc[4][c], acc[5][c], acc[6][c], acc[7][c]);
                *reinterpret_cast<float4*>(T + c * 8)     = lo;  // upper junk never read
                *reinterpret_cast<float4*>(T + c * 8 + 4) = hi;
            }
        }
        __syncthreads();
        if (tk == pb && ti > pb) {
            // panel solve: B := B * Ld^{-T}; result is final L tile (ti,pb)
#pragma unroll
            for (int c = 0; c < 8; ++c) {
#pragma unroll
                for (int m = 0; m < 8; ++m) {
                    if (m < c) {
                        const float coef = Ld_s[c * 8 + m];
#pragma unroll
                        for (int r = 0; r < 8; ++r) acc[r][c] -= acc[r][m] * coef;
                    }
                }
                const float inv = invd_s[kb + c];
#pragma unroll
                for (int r = 0; r < 8; ++r) acc[r][c] *= inv;
            }
            float* T = Lt + TRI(ti, pb) * TSZ;
#pragma unroll
            for (int c = 0; c < 8; ++c) {
                const float4 lo = make_float4(acc[0][c], acc[1][c], acc[2][c], acc[3][c]);
                const float4 hi = make_float4(acc[4][c], acc[5][c], acc[6][c], acc[7][c]);
                *reinterpret_cast<float4*>(T + c * 8)     = lo;
                *reinterpret_cast<float4*>(T + c * 8 + 4) = hi;
            }
        }
        __syncthreads();
        if (ti > pb && tk > pb) {
            // rank-8 trailing update from the freshly published panel tiles
            const float* TA = Lt + TRI(ti, pb) * TSZ;
            const float* TB = Lt + TRI(tk, pb) * TSZ;
#pragma unroll
            for (int m = 0; m < 8; ++m) {
                const float4 c0 = *reinterpret_cast<const float4*>(TA + m * 8);
                const float4 c1 = *reinterpret_cast<const float4*>(TA + m * 8 + 4);
                const float4 d0 = *reinterpret_cast<const float4*>(TB + m * 8);
                const float4 d1 = *reinterpret_cast<const float4*>(TB + m * 8 + 4);
                const float cl[8] = {c0.x, c0.y, c0.z, c0.w, c1.x, c1.y, c1.z, c1.w};
                const float cc[8] = {d0.x, d0.y, d0.z, d0.w, d1.x, d1.y, d1.z, d1.w};
#pragma unroll
                for (int r = 0; r < 8; ++r)
#pragma unroll
                    for (int c = 0; c < 8; ++c) acc[r][c] -= cl[r] * cc[c];
            }
        }
        // no barrier needed: barrier 1 of next iter orders Ld_s/Lt reuse
    }
    __syncthreads();
    // acc is DEAD from here on.

    // ---- Phase 5a: forward block solve L z = Fx (tiles from Lt) ----
    for (int I = 0; I < 16; ++I) {
        if (ti == I && tk < I) {
            // u = L(I,tk) * z[tk-block]
            const float* T = Lt + TRI(I, tk) * TSZ;
            const float4 z0 = *reinterpret_cast<const float4*>(z_s + tk * 8);
            const float4 z1 = *reinterpret_cast<const float4*>(z_s + tk * 8 + 4);
            const float zc[8] = {z0.x, z0.y, z0.z, z0.w, z1.x, z1.y, z1.z, z1.w};
            float u[8];
#pragma unroll
            for (int r = 0; r < 8; ++r) u[r] = 0.0f;
#pragma unroll
            for (int c = 0; c < 8; ++c) {
                const float4 lo = *reinterpret_cast<const float4*>(T + c * 8);
                const float4 hi = *reinterpret_cast<const float4*>(T + c * 8 + 4);
                u[0] += lo.x * zc[c]; u[1] += lo.y * zc[c];
                u[2] += lo.z * zc[c]; u[3] += lo.w * zc[c];
                u[4] += hi.x * zc[c]; u[5] += hi.y * zc[c];
                u[6] += hi.z * zc[c]; u[7] += hi.w * zc[c];
            }
#pragma unroll
            for (int r = 0; r < 8; ++r) red_s[tk * RP + r] = u[r];
        }
        __syncthreads();
        if (ti == I && tk == I) {
            const float* T = Lt + TRI(I, I) * TSZ;
            float w[8];
#pragma unroll
            for (int r = 0; r < 8; ++r) w[r] = Fx_s[I * 8 + r];
            for (int K = 0; K < I; ++K)
#pragma unroll
                for (int r = 0; r < 8; ++r) w[r] -= red_s[K * RP + r];
            float zl[8];
#pragma unroll
            for (int r = 0; r < 8; ++r) {
                float v = w[r];
#pragma unroll
                for (int m = 0; m < 8; ++m)
                    if (m < r) v -= T[m * 8 + r] * zl[m];
                zl[r] = v * invd_s[I * 8 + r];
                z_s[I * 8 + r] = zl[r];
            }
        }
        __syncthreads();
    }

    // ---- Phase 5b: backward block solve L^T y = z (tiles from Lt) ----
    for (int K = 15; K >= 0; --K) {
        if (tk == K && ti > K) {
            // u = L(ti,K)^T * y[ti-block]
            const float* T = Lt + TRI(ti, K) * TSZ;
            const float4 y0 = *reinterpret_cast<const float4*>(y_s + ti * 8);
            const float4 y1 = *reinterpret_cast<const float4*>(y_s + ti * 8 + 4);
            const float yl[8] = {y0.x, y0.y, y0.z, y0.w, y1.x, y1.y, y1.z, y1.w};
#pragma unroll
            for (int c = 0; c < 8; ++c) {
                const float4 lo = *reinterpret_cast<const float4*>(T + c * 8);
                const float4 hi = *reinterpret_cast<const float4*>(T + c * 8 + 4);
                const float u = lo.x * yl[0] + lo.y * yl[1] + lo.z * yl[2] + lo.w * yl[3]
                              + hi.x * yl[4] + hi.y * yl[5] + hi.z * yl[6] + hi.w * yl[7];
                red_s[ti * RP + c] = u;
            }
        }
        __syncthreads();
        if (ti == K && tk == K) {
            const float* T = Lt + TRI(K, K) * TSZ;
            float w[8];
#pragma unroll
            for (int c = 0; c < 8; ++c) w[c] = z_s[K * 8 + c];
            for (int I = K + 1; I < 16; ++I)
#pragma unroll
                for (int c = 0; c < 8; ++c) w[c] -= red_s[I * RP + c];
            float yl[8];
#pragma unroll
            for (int cc = 0; cc < 8; ++cc) {
                const int c = 7 - cc;
                float v = w[c];
#pragma unroll
                for (int m = 0; m < 8; ++m)
                    if (m > c) v -= T[c * 8 + m] * yl[m];
                yl[c] = v * invd_s[K * 8 + c];
                y_s[K * 8 + c] = yl[c];
            }
        }
        __syncthreads();
    }

    // ---- Phase 6: x_new = x - s .* (A^T y) (coalesced over columns) ----
    {
        float sum = 0.0f;
#pragma unroll 8
        for (int i = 0; i < kM; ++i) sum += A[i * kN + tid] * y_s[i];
        out[b * kN + tid] = xv - sv * sum;
    }
}

extern "C" void kernel_launch(void* const* d_in, const int* in_sizes, int n_in,
                              void* d_out, int out_size, void* d_ws, size_t ws_size,
                              hipStream_t stream) {
    const float* x     = (const float*)d_in[0];
    const float* parms = (const float*)d_in[1];
    const float* A     = (const float*)d_in[2];
    float* out = (float*)d_out;
    const int Bcount = in_sizes[0] / kN;  // 2048
    eqcon_kernel<<<dim3(Bcount), dim3(256), 0, stream>>>(x, parms, A, out);
}

// Round 9
// 804.462 us; speedup vs baseline: 1.3938x; 1.3938x over previous
//
#include <hip/hip_runtime.h>
#include <math.h>

// EqualityConstraint: x_new = x - J^T G^{-1} F(x)
//   t = tanh(x); s = 1 - t^2; J = A diag(s)
//   F = A t + p; G = A diag(s^2) A^T  (SPD, M x M)
//   y = G^{-1} F;  x_new = x - s .* (A^T y)
//
// One 256-thread block per batch row; 16x16 thread grid, each thread an 8x8
// register tile of G -> L (blocked right-looking register Cholesky);
// compact triangular LDS L-tile buffer; wave-serial triangular solves.
//
// LAWS MEASURED OVER R1-R8 (this toolchain, gfx950):
//  RESIDENCY: resident blocks/CU = __launch_bounds__ 2nd arg (default 1!).
//    none->12% occ, 2->22%, 3->32%, 4->46%. Never resource-derived upward.
//  VGPR BUDGET: compiler cap = 256/N for 2nd arg N. Natural demand of this
//    kernel = 148 (R8, unconstrained, zero scratch). Any cap <=85 spills
//    acc[8][8] wholesale -> GBs of scratch, kernel becomes scratch-bound
//    (R2/R3/R6/R7). Cap 128 fits cleanly (R1/R5). => (256,2) is the only
//    clean point with 64-reg accumulators.
//  BANK: stage chunk-swizzle psi(i)=i+4*(i>>5) pitch 140 -> 2-way (free);
//    TSZ=68 tiles rotate tile-base banks -> 2-way on trailing reads.
//    Conflicts: R5 (TSZ64) 7.1e7 -> R8 (swz+68) 2.05e7.
//  BARRIERS: distributed block solves cost 64 barriers; wave-serial solve
//    (R1) needs 2 and its serial chain (~5us/problem) hides under the
//    other resident block. This version: R8 layout + (256,2) + wave-serial.

#define kN 256   // x dim
#define kM 128   // constraint dim
#define SP  140  // swizzled stage row pitch (floats); psi(127)=139 < 140
#define TSZ 68   // L-tile stride in floats (17 float4s)
#define TRI(I,K) ((((I) * ((I) + 1)) >> 1) + (K))   // lower-tri tile index, I>=K

__global__ __launch_bounds__(256, 2)
void eqcon_kernel(const float* __restrict__ x,
                  const float* __restrict__ parms,
                  const float* __restrict__ A,
                  float* __restrict__ out)
{
    __shared__ float Fx_s[kM];
    __shared__ float z_s[kM];
    __shared__ float y_s[kM];
    __shared__ float invd_s[kM];
    __shared__ float Ld_s[64];
    // Phases 1-3: [0..2240) swizzled A-stage, [2240..2496) t, [2496..2752) s.
    // Phase 4+:  L tiles, tile (I,K) I>=K at TRI(I,K)*TSZ, col-major
    //            T[c*8+r] = L_tile[r][c]. Tile writes only reach the aliased
    //            region after stage/t/s are dead (post-phase-3 barrier).
    __shared__ float pool[136 * TSZ];   // 9248 floats = 36992 B

    const int tid = (int)threadIdx.x;
    const int b   = (int)blockIdx.x;
    const int ti  = tid & 15;   // row-tile index
    const int tk  = tid >> 4;   // col-tile index

    float* stage = pool;
    float* t_sh  = pool + 16 * SP;        // 2240
    float* s_sh  = pool + 16 * SP + kN;   // 2496

    // ---- Phase 1: t = tanh(x), s = sech^2(x) ----
    const float xv = x[b * kN + tid];
    const float tv = tanhf(xv);
    const float sv = 1.0f - tv * tv;
    t_sh[tid] = tv;
    s_sh[tid] = sv;
    __syncthreads();

    // ---- Phase 2: Fx = A t + parms (2 threads per row) ----
    {
        const int row  = tid >> 1;
        const int half = tid & 1;
        const float4* __restrict__ Ar =
            reinterpret_cast<const float4*>(A + row * kN + half * (kN / 2));
        const float4* Tr = reinterpret_cast<const float4*>(t_sh + half * (kN / 2));
        float sum = 0.0f;
#pragma unroll
        for (int q = 0; q < kN / 8; ++q) {
            const float4 a4 = Ar[q];
            const float4 t4 = Tr[q];
            sum += a4.x * t4.x + a4.y * t4.y + a4.z * t4.z + a4.w * t4.w;
        }
        sum += __shfl_xor(sum, 1);
        if (half == 0) Fx_s[row] = sum + parms[b * kM + row];
    }

    // ---- Phase 3: G = A diag(s^2) A^T, each thread an 8x8 register tile ----
    float acc[8][8];
#pragma unroll
    for (int r = 0; r < 8; ++r)
#pragma unroll
        for (int c = 0; c < 8; ++c) acc[r][c] = 0.0f;

    // swizzled read bases: chunk(i>>2) -> chunk + (chunk>>3), float4-aligned
    const int aoff = ti * 8 + ((ti >> 2) << 2);
    const int boff = tk * 8 + ((tk >> 2) << 2);

    for (int jt = 0; jt < kN; jt += 16) {
        __syncthreads();  // prev tile's compute done before overwriting stage
#pragma unroll
        for (int rep = 0; rep < 8; ++rep) {
            const int idx = rep * 256 + tid;
            const int i   = idx >> 4;
            const int jj  = idx & 15;
            stage[jj * SP + i + ((i >> 5) << 2)] = A[i * kN + (jt + jj)];
        }
        __syncthreads();
#pragma unroll
        for (int jj = 0; jj < 16; ++jj) {
            const float sj = s_sh[jt + jj];
            const float w  = sj * sj;
            const float* rowp = stage + jj * SP;
            const float4 a0 = *reinterpret_cast<const float4*>(rowp + aoff);
            const float4 a1 = *reinterpret_cast<const float4*>(rowp + aoff + 4);
            const float4 b0 = *reinterpret_cast<const float4*>(rowp + boff);
            const float4 b1 = *reinterpret_cast<const float4*>(rowp + boff + 4);
            const float av[8] = {a0.x, a0.y, a0.z, a0.w, a1.x, a1.y, a1.z, a1.w};
            const float bv[8] = {b0.x * w, b0.y * w, b0.z * w, b0.w * w,
                                 b1.x * w, b1.y * w, b1.z * w, b1.w * w};
#pragma unroll
            for (int r = 0; r < 8; ++r)
#pragma unroll
                for (int c = 0; c < 8; ++c) acc[r][c] += av[r] * bv[c];
        }
    }
    __syncthreads();  // stage/t/s dead; pool becomes the L-tile buffer

    float* Lt = pool;

    // ---- Phase 4: blocked register Cholesky; L tiles published to Lt ----
    for (int pb = 0; pb < 16; ++pb) {
        const int kb = pb * 8;
        if (ti == pb && tk == pb) {
            // 8x8 diagonal Cholesky in registers (lower triangle)
#pragma unroll
            for (int kk = 0; kk < 8; ++kk) {
                float d = fmaxf(acc[kk][kk], 1e-30f);
                const float rd  = sqrtf(d);
                const float inv = 1.0f / rd;
                invd_s[kb + kk] = inv;
                acc[kk][kk] = rd;
#pragma unroll
                for (int r = kk + 1; r < 8; ++r) acc[r][kk] *= inv;
#pragma unroll
                for (int r = kk + 1; r < 8; ++r)
#pragma unroll
                    for (int c = kk + 1; c <= r; ++c)
                        acc[r][c] -= acc[r][kk] * acc[c][kk];
            }
#pragma unroll
            for (int r = 0; r < 8; ++r)
#pragma unroll
                for (int c = 0; c < 8; ++c) Ld_s[r * 8 + c] = acc[r][c];
            float* T = Lt + TRI(pb, pb) * TSZ;
#pragma unroll
            for (int c = 0; c < 8; ++c) {
                const float4 lo = make_float4(acc[0][c], acc[1][c], acc[2][c], acc[3][c]);
                const float4 hi = make_float4(acc[4][c], acc[5][c], acc[6][c], acc[7][c]);
                *reinterpret_cast<float4*>(T + c * 8)     = lo;  // upper junk never read
                *reinterpret_cast<float4*>(T + c * 8 + 4) = hi;
            }
        }
        __syncthreads();
        if (tk == pb && ti > pb) {
            // panel solve: B := B * Ld^{-T}; result is final L tile (ti,pb)
#pragma unroll
            for (int c = 0; c < 8; ++c) {
#pragma unroll
                for (int m = 0; m < 8; ++m) {
                    if (m < c) {
                        const float coef = Ld_s[c * 8 + m];
#pragma unroll
                        for (int r = 0; r < 8; ++r) acc[r][c] -= acc[r][m] * coef;
                    }
                }
                const float inv = invd_s[kb + c];
#pragma unroll
                for (int r = 0; r < 8; ++r) acc[r][c] *= inv;
            }
            float* T = Lt + TRI(ti, pb) * TSZ;
#pragma unroll
            for (int c = 0; c < 8; ++c) {
                const float4 lo = make_float4(acc[0][c], acc[1][c], acc[2][c], acc[3][c]);
                const float4 hi = make_float4(acc[4][c], acc[5][c], acc[6][c], acc[7][c]);
                *reinterpret_cast<float4*>(T + c * 8)     = lo;
                *reinterpret_cast<float4*>(T + c * 8 + 4) = hi;
            }
        }
        __syncthreads();
        if (ti > pb && tk > pb) {
            // rank-8 trailing update from the freshly published panel tiles
            const float* TA = Lt + TRI(ti, pb) * TSZ;
            const float* TB = Lt + TRI(tk, pb) * TSZ;
#pragma unroll
            for (int m = 0; m < 8; ++m) {
                const float4 c0 = *reinterpret_cast<const float4*>(TA + m * 8);
                const float4 c1 = *reinterpret_cast<const float4*>(TA + m * 8 + 4);
                const float4 d0 = *reinterpret_cast<const float4*>(TB + m * 8);
                const float4 d1 = *reinterpret_cast<const float4*>(TB + m * 8 + 4);
                const float cl[8] = {c0.x, c0.y, c0.z, c0.w, c1.x, c1.y, c1.z, c1.w};
                const float cc[8] = {d0.x, d0.y, d0.z, d0.w, d1.x, d1.y, d1.z, d1.w};
#pragma unroll
                for (int r = 0; r < 8; ++r)
#pragma unroll
                    for (int c = 0; c < 8; ++c) acc[r][c] -= cl[r] * cc[c];
            }
        }
        // no barrier needed: barrier 1 of next iter orders Ld_s/Lt reuse
    }
    __syncthreads();
    // acc is DEAD from here on.

    // ---- Phase 5: wave-serial triangular solves on wave 0 (2 rows/lane) ----
    // L[r][k] (r>=k) lives at Lt[TRI(r>>3,k>>3)*TSZ + (k&7)*8 + (r&7)].
    if (tid < 64) {
        const int r0 = tid;
        const int r1 = tid + 64;
        float a0 = Fx_s[r0];
        float a1 = Fx_s[r1];
        // forward: L z = Fx
        for (int k = 0; k < kM; ++k) {
            const float srcv = (k < 64) ? a0 : a1;
            const float zk = __shfl(srcv, k & 63) * invd_s[k];
            if (tid == (k & 63)) z_s[k] = zk;
            const float l0 = Lt[TRI(r0 >> 3, k >> 3) * TSZ + (k & 7) * 8 + (r0 & 7)];
            const float l1 = Lt[TRI(r1 >> 3, k >> 3) * TSZ + (k & 7) * 8 + (r1 & 7)];
            if (r0 > k) a0 -= l0 * zk;
            a1 -= (r1 > k) ? l1 * zk : 0.0f;
        }
        a0 = z_s[r0];
        a1 = z_s[r1];
        // backward: L^T y = z   (uses L[k][r], k>=r)
        for (int k = kM - 1; k >= 0; --k) {
            const float srcv = (k < 64) ? a0 : a1;
            const float yk = __shfl(srcv, k & 63) * invd_s[k];
            if (tid == (k & 63)) y_s[k] = yk;
            const float u0 = Lt[TRI(k >> 3, r0 >> 3) * TSZ + (r0 & 7) * 8 + (k & 7)];
            const float u1 = Lt[TRI(k >> 3, r1 >> 3) * TSZ + (r1 & 7) * 8 + (k & 7)];
            if (r0 < k) a0 -= u0 * yk;
            if (r1 < k) a1 -= u1 * yk;
        }
    }
    __syncthreads();

    // ---- Phase 6: x_new = x - s .* (A^T y) (coalesced over columns) ----
    {
        float sum = 0.0f;
#pragma unroll 8
        for (int i = 0; i < kM; ++i) sum += A[i * kN + tid] * y_s[i];
        out[b * kN + tid] = xv - sv * sum;
    }
}

extern "C" void kernel_launch(void* const* d_in, const int* in_sizes, int n_in,
                              void* d_out, int out_size, void* d_ws, size_t ws_size,
                              hipStream_t stream) {
    const float* x     = (const float*)d_in[0];
    const float* parms = (const float*)d_in[1];
    const float* A     = (const float*)d_in[2];
    float* out = (float*)d_out;
    const int Bcount = in_sizes[0] / kN;  // 2048
    eqcon_kernel<<<dim3(Bcount), dim3(256), 0, stream>>>(x, parms, A, out);
}